// Round 14
// baseline (463.173 us; speedup 1.0000x reference)
//
#include <hip/hip_runtime.h>

#define NB 128   // batch
#define NS 128   // context seq len
#define NT 12    // target seq len
#define NE 300   // embed dim
#define NH 512   // hidden
#define NCOL 2048  // 4*NH
#define WGSC __HIP_MEMORY_SCOPE_WORKGROUP

typedef _Float16 h8v __attribute__((ext_vector_type(8)));
typedef __attribute__((ext_vector_type(4))) float f4v;
typedef __attribute__((ext_vector_type(4))) int   i4v;

__device__ __forceinline__ unsigned short f2h(float f) {
  union { _Float16 h; unsigned short u; } c; c.h = (_Float16)f; return c.u;
}
__device__ __forceinline__ float sigm(float x) { return 1.f / (1.f + __expf(-x)); }
__device__ __forceinline__ float tanh_(float x) { const float e = __expf(2.f * x); return 1.f - 2.f / (e + 1.f); }

// pack two f16 h-values into a dword, stealing each mantissa LSB for a 2-bit step tag
__device__ __forceinline__ unsigned packh(float a, float b, int tag) {
  unsigned lo = f2h(a), hi = f2h(b);
  lo = (lo & ~1u) | (unsigned)(tag & 1);
  hi = (hi & ~1u) | (unsigned)((tag >> 1) & 1);
  return lo | (hi << 16);
}

// ---- device-scope UNCACHED (sc1, coherence at IF/L3) primitives ----
__device__ __forceinline__ void st32f_uc(float* p, float v) {
  asm volatile("global_store_dword %0, %1, off sc1" :: "v"(p), "v"(v) : "memory");
}
__device__ __forceinline__ void st32i_uc(int* p, int v) {
  asm volatile("global_store_dword %0, %1, off sc1" :: "v"(p), "v"(v) : "memory");
}
__device__ __forceinline__ void st32u_uc(unsigned* p, unsigned v) {
  asm volatile("global_store_dword %0, %1, off sc1" :: "v"(p), "v"(v) : "memory");
}
__device__ __forceinline__ int ldflag(const int* p) {
  int v;
  asm volatile("global_load_dword %0, %1, off sc1\n\ts_waitcnt vmcnt(0)" : "=v"(v) : "v"(p) : "memory");
  return v;
}
__device__ __forceinline__ unsigned ld4_uc(const char* a) {
  unsigned v;
  asm volatile("global_load_dword %0, %1, off sc1\n\ts_waitcnt vmcnt(0)" : "=v"(v) : "v"(a) : "memory");
  return v;
}
// 4 x 16B sc1 loads of one contiguous 64B chunk, one vmcnt
__device__ __forceinline__ void ld64_uc(const char* a, i4v* r) {
  asm volatile(
    "global_load_dwordx4 %0, %4, off sc1\n\t"
    "global_load_dwordx4 %1, %4, off offset:16 sc1\n\t"
    "global_load_dwordx4 %2, %4, off offset:32 sc1\n\t"
    "global_load_dwordx4 %3, %4, off offset:48 sc1\n\t"
    "s_waitcnt vmcnt(0)"
    : "=&v"(r[0]), "=&v"(r[1]), "=&v"(r[2]), "=&v"(r[3])
    : "v"(a) : "memory");
}

struct Params {
  const int *tids, *tlen, *lids, *llen, *rids, *rlen;
  const float *emb, *Wl, *bl, *Wr, *br, *Wd, *bd;
  float* out;
  unsigned short* hbuf;  // [2(pp)][2(side)][NB][NH] f16 tagged (sc1; zeroed each launch)
  float* hfin;           // [2(side)][NB][NH] fp32 (sc1)
  int* bar;              // flags: [16 groups] x 4KB page (epilogue only)
};

__device__ __forceinline__ void lspin(int* c, int tgt) {
  while (__hip_atomic_load(c, __ATOMIC_RELAXED, WGSC) < tgt) {}
  __builtin_amdgcn_fence(__ATOMIC_ACQUIRE, "workgroup");
}
// sleepy variant for x-role waits (frees SIMD issue slots for co-resident h-wave)
__device__ __forceinline__ void lspin_s(int* c, int tgt) {
  while (__hip_atomic_load(c, __ATOMIC_RELAXED, WGSC) < tgt)
    __builtin_amdgcn_s_sleep(1);
  __builtin_amdgcn_fence(__ATOMIC_ACQUIRE, "workgroup");
}
__device__ __forceinline__ void larrive(int* c) {
  __hip_atomic_fetch_add(c, 1, __ATOMIC_ACQ_REL, WGSC);
}

// LDS layout (main loop):
//   HS   @ 0     : 16 rows x 1024B f16, XOR-swizzled (h staging)   16384
//   XS   @ 16384 : 16 rows x 640B f16, XOR-swizzled (x staging)    10240
//   ZX   @ 26624 : 3-slot ring, [16][128] f32 (8KB/slot)           24576
//   ZS   @ 51200 : [16][128] f32 gate exchange                      8192
// prologue aliases (dead before first conflicting use):
//   meanF16 [16][640B swizzled] @ OFF_HS (dead before t=1 h staging)
//   WTH @ 51200 (ZS) ; WTX @ 34816 (ZX slot1)
#define OFF_HS   0
#define OFF_XS   16384
#define OFF_ZX   26624
#define OFF_ZS   51200
#define OFF_WTH  51200
#define OFF_WTX  34816
#define LDS_SZ   59392

__global__ __launch_bounds__(512, 1) void lstm_all(Params p) {
  __shared__ __align__(16) char lds[LDS_SZ];
  __shared__ int lenL[16];
  __shared__ float redL[8][4];
  __shared__ int cnt[8];   // 0:stage 1:xbar 2:prod 3:cons 4:zsbar 5:epi 7:hpbar

  const int tid = threadIdx.x;
  const int wid = blockIdx.x;
  if (tid < 8) cnt[tid] = 0;

  // group g = wid&15 (side=g&1, bt=g>>1: 16 batch rows), dim-block ht = wid>>4 (32 dims)
  const int g = wid & 15, ht = wid >> 4;
  const int side = g & 1, bt = g >> 1;
  const int b0 = bt * 16, d0c = ht * 32;
  const int* lenp = side ? p.rlen : p.llen;
  const int* gids = side ? p.rids : p.lids;
  const float* W = side ? p.Wr : p.Wl;
  const float* bias = side ? p.br : p.bl;
  int* fl = p.bar + g * 1024;

  const bool isH = tid < 256;          // waves 0-3: h recurrence; 4-7: x pipeline
  const int wv = tid >> 6;
  const int ln = tid & 63;
  const int lwv = isH ? wv : (wv - 4); // role-local wave = GATE index (0..3)
  const int kgrp = ln >> 4;
  const int stid = tid & 255;

  float* zS = (float*)(lds + OFF_ZS);

  // ---------------- phase 1: mean_t -> f16 row-major swizzled @ OFF_HS ----------------
  {
    const int r = tid >> 5, l32 = tid & 31;
    const int b = b0 + r;
    const int Lt = p.tlen[b];
    const float inv = 1.f / (float)Lt;
    int toks[NT];
    #pragma unroll
    for (int t = 0; t < NT; ++t) toks[t] = p.tids[b * NT + t];
    char* mrow = lds + OFF_HS + r * 640;
    for (int k = l32; k < 320; k += 32) {
      unsigned short hv = 0;
      if (k < 300) {
        float s = 0.f;
        #pragma unroll
        for (int t = 0; t < NT; ++t)
          if (t < Lt) s += p.emb[(size_t)toks[t] * NE + k];
        hv = f2h(s * inv);
      }
      const int c16 = k >> 3;
      *(unsigned short*)(mrow + ((c16 * 16) ^ ((r & 7) << 4)) + (k & 7) * 2) = hv;
    }
    if (tid < 16) lenL[tid] = lenp[b0 + tid];
  }
  __syncthreads();   // the ONLY block-wide barrier before the dense head

  if (isH) {
    // ================= h role (waves 0-3; wave w owns gate w) =================
    const int row_c = stid >> 4;       // cell row 0..15
    const int m = stid & 15;           // cell dim pair (2m, 2m+1)
    const int a_r = ln & 15;           // A-frag row

    int he = 0;
    auto hpbar = [&]() {
      ++he;
      if (ln == 0) larrive(&cnt[7]);
      while (__hip_atomic_load(&cnt[7], __ATOMIC_RELAXED, WGSC) < 4 * he) {}
      __builtin_amdgcn_fence(__ATOMIC_ACQUIRE, "workgroup");
    };

    // -------- phase 3m: Wm (W rows 300..619) -> transient frags, zb via MFMA --------
    float zb1[4], zb2[4];
    {
      h8v mfr0[10], mfr1[10];
      unsigned short* wT = (unsigned short*)(lds + OFF_WTH);   // [128 cols][32 k]
      const int r3 = stid >> 3;
      const int part = stid & 7;
      const int gate_p = part >> 1, half_p = part & 1;
      for (int i = 0; i < 10; ++i) {
        const int k = 300 + i * 32 + r3;    // <= 619, valid memory
        const float* wr = W + (size_t)k * NCOL + gate_p * NH + d0c + half_p * 16;
        const f4v a0 = *(const f4v*)wr;
        const f4v a1 = *(const f4v*)(wr + 4);
        const f4v a2 = *(const f4v*)(wr + 8);
        const f4v a3 = *(const f4v*)(wr + 12);
        #pragma unroll
        for (int j = 0; j < 4; ++j) {
          wT[(part * 16 + j) * 32 + r3]      = f2h(a0[j]);
          wT[(part * 16 + 4 + j) * 32 + r3]  = f2h(a1[j]);
          wT[(part * 16 + 8 + j) * 32 + r3]  = f2h(a2[j]);
          wT[(part * 16 + 12 + j) * 32 + r3] = f2h(a3[j]);
        }
        hpbar();
        const int c0 = lwv * 32 + (ln & 15);
        mfr0[i] = *(const h8v*)((char*)wT + c0 * 64 + kgrp * 16);
        mfr1[i] = *(const h8v*)((char*)wT + (c0 + 16) * 64 + kgrp * 16);
        hpbar();
      }
      f4v acc0 = {0.f, 0.f, 0.f, 0.f}, acc1 = {0.f, 0.f, 0.f, 0.f};
      #pragma unroll
      for (int kt = 0; kt < 10; ++kt) {
        h8v a = *(const h8v*)(lds + OFF_HS + a_r * 640
                              + (((kt * 4 + kgrp) * 16) ^ ((a_r & 7) << 4)));
        acc0 = __builtin_amdgcn_mfma_f32_16x16x32_f16(a, mfr0[kt], acc0, 0, 0, 0);
        acc1 = __builtin_amdgcn_mfma_f32_16x16x32_f16(a, mfr1[kt], acc1, 0, 0, 0);
      }
      #pragma unroll
      for (int rg = 0; rg < 4; ++rg) {
        const int rr = kgrp * 4 + rg;
        zS[rr * 128 + lwv * 32 + (ln & 15)]      = acc0[rg];
        zS[rr * 128 + lwv * 32 + 16 + (ln & 15)] = acc1[rg];
      }
      hpbar();
      #pragma unroll
      for (int gq = 0; gq < 4; ++gq) {
        zb1[gq] = zS[row_c * 128 + gq * 32 + 2 * m]     + bias[gq * NH + d0c + 2 * m];
        zb2[gq] = zS[row_c * 128 + gq * 32 + 2 * m + 1] + bias[gq * NH + d0c + 2 * m + 1];
      }
      hpbar();   // zb reads retired before phase 3h reuses WTH (= zS region)
    }

    // -------- phase 3h: Wh -> register B-fragments (16 K-tiles x 2 N-tiles) --------
    h8v hfr0[16], hfr1[16];
    {
      unsigned short* wT = (unsigned short*)(lds + OFF_WTH);   // [128 cols][32 k]
      const int r3 = stid >> 3;
      const int part = stid & 7;
      const int gate_p = part >> 1, half_p = part & 1;
      for (int i = 0; i < 16; ++i) {
        const int k = 600 + i * 32 + r3;
        const float* wr = W + (size_t)k * NCOL + gate_p * NH + d0c + half_p * 16;
        const f4v a0 = *(const f4v*)wr;
        const f4v a1 = *(const f4v*)(wr + 4);
        const f4v a2 = *(const f4v*)(wr + 8);
        const f4v a3 = *(const f4v*)(wr + 12);
        #pragma unroll
        for (int j = 0; j < 4; ++j) {
          wT[(part * 16 + j) * 32 + r3]      = f2h(a0[j]);
          wT[(part * 16 + 4 + j) * 32 + r3]  = f2h(a1[j]);
          wT[(part * 16 + 8 + j) * 32 + r3]  = f2h(a2[j]);
          wT[(part * 16 + 12 + j) * 32 + r3] = f2h(a3[j]);
        }
        hpbar();
        const int c0 = lwv * 32 + (ln & 15);
        hfr0[i] = *(const h8v*)((char*)wT + c0 * 64 + kgrp * 16);
        hfr1[i] = *(const h8v*)((char*)wT + (c0 + 16) * 64 + kgrp * 16);
        hpbar();
      }
    }

    // -------- main recurrence --------
    float cR1 = 0.f, cR2 = 0.f, hR1 = 0.f, hR2 = 0.f;
    const int srow = stid >> 4;                      // staging row (== row_c)
    const int schk = stid & 15;                      // staging 64B chunk
    for (int t = 0; t < NS; ++t) {
      // 1. zx(t) from ring
      lspin(&cnt[2], 4 * (t + 1));
      const float* zx = (const float*)(lds + OFF_ZX + (t % 3) * 8192);
      f4v acc0, acc1;
      #pragma unroll
      for (int rg = 0; rg < 4; ++rg) {
        const int rr = kgrp * 4 + rg;
        acc0[rg] = zx[rr * 128 + lwv * 32 + (ln & 15)];
        acc1[rg] = zx[rr * 128 + lwv * 32 + 16 + (ln & 15)];
      }
      if (ln == 0) larrive(&cnt[3]);

      // 2. two-phase poll: (A) 4B tag probe (16x less fabric traffic),
      //    (B) full 64B fetch + validate. Then stage -> HS, barrier, MFMA.
      if (t) {
        const char* src = (const char*)(p.hbuf
            + (size_t)(((t & 1) * 2 + side) * NB + b0 + srow) * NH + schk * 32);
        const unsigned exp32 = ((unsigned)(t & 1)) | (((unsigned)((t >> 1) & 1)) << 16);
        // phase A: probe dword 0 of my chunk
        for (;;) {
          unsigned pv = ld4_uc(src);
          if (!((pv ^ exp32) & 0x00010001u)) break;
        }
        // phase B: fetch + validate all 16 dwords (chunk written by one producer
        // wave's single store instruction -> almost always valid on first fetch)
        i4v v[4];
        for (;;) {
          ld64_uc(src, v);
          unsigned bad = 0;
          #pragma unroll
          for (int q = 0; q < 4; ++q)
            #pragma unroll
            for (int j = 0; j < 4; ++j)
              bad |= (((unsigned)v[q][j]) ^ exp32) & 0x00010001u;
          if (!bad) break;
        }
        #pragma unroll
        for (int q = 0; q < 4; ++q) {
          const int c16 = schk * 4 + q;
          *(i4v*)(lds + OFF_HS + srow * 1024 + ((c16 * 16) ^ ((srow & 7) << 4))) = v[q];
        }
        if (ln == 0) larrive(&cnt[0]);
        while (__hip_atomic_load(&cnt[0], __ATOMIC_RELAXED, WGSC) < 4 * t) {}
        __builtin_amdgcn_fence(__ATOMIC_ACQUIRE, "workgroup");
        #pragma unroll
        for (int kt = 0; kt < 16; ++kt) {
          h8v a = *(const h8v*)(lds + OFF_HS + a_r * 1024
                                + (((kt * 4 + kgrp) * 16) ^ ((a_r & 7) << 4)));
          acc0 = __builtin_amdgcn_mfma_f32_16x16x32_f16(a, hfr0[kt], acc0, 0, 0, 0);
          acc1 = __builtin_amdgcn_mfma_f32_16x16x32_f16(a, hfr1[kt], acc1, 0, 0, 0);
        }
      }

      // 3. gate exchange (wave w -> zS cols of gate w)
      #pragma unroll
      for (int rg = 0; rg < 4; ++rg) {
        const int rr = kgrp * 4 + rg;
        zS[rr * 128 + lwv * 32 + (ln & 15)]      = acc0[rg];
        zS[rr * 128 + lwv * 32 + 16 + (ln & 15)] = acc1[rg];
      }
      if (ln == 0) larrive(&cnt[4]);
      while (__hip_atomic_load(&cnt[4], __ATOMIC_RELAXED, WGSC) < 4 * (t + 1)) {}
      __builtin_amdgcn_fence(__ATOMIC_ACQUIRE, "workgroup");

      // 4. cell update (row_c, dims 2m/2m+1); tagged coalesced dword store, NO drain/flag
      {
        const float* zr = zS + row_c * 128;
        float zi = zr[0 * 32 + 2 * m] + zb1[0], zj = zr[1 * 32 + 2 * m] + zb1[1];
        float zf = zr[2 * 32 + 2 * m] + zb1[2], zo = zr[3 * 32 + 2 * m] + zb1[3];
        float ig = sigm(zi), jg = tanh_(zj), fg = sigm(zf + 1.f), og = sigm(zo);
        float cn = fg * cR1 + ig * jg;
        float hn = og * tanh_(cn);
        if (t < lenL[row_c]) { cR1 = cn; hR1 = hn; }
        zi = zr[0 * 32 + 2 * m + 1] + zb2[0]; zj = zr[1 * 32 + 2 * m + 1] + zb2[1];
        zf = zr[2 * 32 + 2 * m + 1] + zb2[2]; zo = zr[3 * 32 + 2 * m + 1] + zb2[3];
        ig = sigm(zi); jg = tanh_(zj); fg = sigm(zf + 1.f); og = sigm(zo);
        cn = fg * cR2 + ig * jg; hn = og * tanh_(cn);
        if (t < lenL[row_c]) { cR2 = cn; hR2 = hn; }
        unsigned pk = packh(hR1, hR2, (t + 1) & 3);
        unsigned* dst = (unsigned*)p.hbuf
            + ((size_t)((((t + 1) & 1) * 2 + side) * NB + b0 + row_c) * (NH / 2)) + d0c / 2 + m;
        st32u_uc(dst, pk);
      }
    }

    // -------- epilogue: final h -> hfin (sc1, clean fp32), then flag NS+1 --------
    st32f_uc(&p.hfin[((size_t)side * NB + b0 + row_c) * NH + d0c + 2 * m], hR1);
    st32f_uc(&p.hfin[((size_t)side * NB + b0 + row_c) * NH + d0c + 2 * m + 1], hR2);
    asm volatile("s_waitcnt vmcnt(0)" ::: "memory");
    if (ln == 0) larrive(&cnt[5]);
    if (lwv == 0) {
      while (__hip_atomic_load(&cnt[5], __ATOMIC_RELAXED, WGSC) < 4) {}
      if (ln == 0) st32i_uc(fl + ht, NS + 1);
    }
  } else {
    // ================= x role (waves 4-7; wave owns gate lwv) =================
    int xe = 0;
    auto xbar = [&]() {
      ++xe;
      if (ln == 0) larrive(&cnt[1]);
      while (__hip_atomic_load(&cnt[1], __ATOMIC_RELAXED, WGSC) < 4 * xe)
        __builtin_amdgcn_s_sleep(1);
      __builtin_amdgcn_fence(__ATOMIC_ACQUIRE, "workgroup");
    };

    // -------- phase 3x: Wx -> register B-fragments (10 K-tiles x 2 N-tiles) --------
    h8v xfr0[10], xfr1[10];
    {
      unsigned short* wT = (unsigned short*)(lds + OFF_WTX);   // [128 cols][32 k]
      const int r3 = stid >> 3, part = stid & 7;
      const int gate_p = part >> 1, half_p = part & 1;
      for (int i = 0; i < 10; ++i) {
        const int k = i * 32 + r3;
        float v[16];
        if (k < NE) {
          const float* wr = W + (size_t)k * NCOL + gate_p * NH + d0c + half_p * 16;
          const f4v a0 = *(const f4v*)wr;
          const f4v a1 = *(const f4v*)(wr + 4);
          const f4v a2 = *(const f4v*)(wr + 8);
          const f4v a3 = *(const f4v*)(wr + 12);
          #pragma unroll
          for (int j = 0; j < 4; ++j) {
            v[j] = a0[j]; v[4 + j] = a1[j]; v[8 + j] = a2[j]; v[12 + j] = a3[j];
          }
        } else {
          #pragma unroll
          for (int j = 0; j < 16; ++j) v[j] = 0.f;
        }
        #pragma unroll
        for (int j = 0; j < 16; ++j)
          wT[(part * 16 + j) * 32 + r3] = f2h(v[j]);
        xbar();
        const int c0 = lwv * 32 + (ln & 15);
        xfr0[i] = *(const h8v*)((char*)wT + c0 * 64 + kgrp * 16);
        xfr1[i] = *(const h8v*)((char*)wT + (c0 + 16) * 64 + kgrp * 16);
        xbar();
      }
    }

    // -------- x pipeline: produce zx(n) = x_n @ Wx, up to 3 ahead --------
    for (int n = 0; n < NS; ++n) {
      if (n >= 3) lspin_s(&cnt[3], 4 * (n - 2));   // ring slot n%3 free (sleepy)
      {
        const int xrow = stid >> 4;              // 16 rows, 16 lanes each
        const int tok = gids[(size_t)(b0 + xrow) * NS + n];
        const float* ep_ = p.emb + (size_t)tok * NE;
        #pragma unroll
        for (int j = 0; j < 3; ++j) {
          const int c16 = (stid & 15) + j * 16;
          if (c16 < 40) {
            unsigned short tmp[8];
            if (c16 < 37) {
              const f4v v0 = *(const f4v*)(ep_ + c16 * 8);
              const f4v v1 = *(const f4v*)(ep_ + c16 * 8 + 4);
              tmp[0] = f2h(v0[0]); tmp[1] = f2h(v0[1]); tmp[2] = f2h(v0[2]); tmp[3] = f2h(v0[3]);
              tmp[4] = f2h(v1[0]); tmp[5] = f2h(v1[1]); tmp[6] = f2h(v1[2]); tmp[7] = f2h(v1[3]);
            } else if (c16 == 37) {
              const f4v v0 = *(const f4v*)(ep_ + 296);
              tmp[0] = f2h(v0[0]); tmp[1] = f2h(v0[1]); tmp[2] = f2h(v0[2]); tmp[3] = f2h(v0[3]);
              tmp[4] = 0; tmp[5] = 0; tmp[6] = 0; tmp[7] = 0;
            } else {
              #pragma unroll
              for (int q = 0; q < 8; ++q) tmp[q] = 0;
            }
            *(i4v*)(lds + OFF_XS + xrow * 640 + ((c16 * 16) ^ ((xrow & 7) << 4))) = *(const i4v*)tmp;
          }
        }
      }
      xbar();
      f4v a0 = {0.f, 0.f, 0.f, 0.f}, a1 = {0.f, 0.f, 0.f, 0.f};
      const int a_r = ln & 15;
      #pragma unroll
      for (int kt = 0; kt < 10; ++kt) {
        h8v a = *(const h8v*)(lds + OFF_XS + a_r * 640
                              + (((kt * 4 + kgrp) * 16) ^ ((a_r & 7) << 4)));
        a0 = __builtin_amdgcn_mfma_f32_16x16x32_f16(a, xfr0[kt], a0, 0, 0, 0);
        a1 = __builtin_amdgcn_mfma_f32_16x16x32_f16(a, xfr1[kt], a1, 0, 0, 0);
      }
      float* zx = (float*)(lds + OFF_ZX + (n % 3) * 8192);
      #pragma unroll
      for (int rg = 0; rg < 4; ++rg) {
        const int rr = kgrp * 4 + rg;
        zx[rr * 128 + lwv * 32 + (ln & 15)]      = a0[rg];
        zx[rr * 128 + lwv * 32 + 16 + (ln & 15)] = a1[rg];
      }
      if (ln == 0) larrive(&cnt[2]);
      xbar();   // xS reads retired before next gather
    }
  }

  // ---------------- dense head (blocks 0..127, all 512 threads) ----------------
  if (wid < NB) {
    const int b = wid, bth = b >> 4;
    if (tid < 32) {
      const int gh = (bth << 1) + (tid >> 4);    // side = tid>>4
      const int* f = p.bar + gh * 1024 + (tid & 15);
      int v = ldflag(f);
      while (__ballot(v < NS + 1) != 0ull) { __builtin_amdgcn_s_sleep(2); v = ldflag(f); }
    }
    __syncthreads();

    float a0 = 0.f, a1 = 0.f, a2 = 0.f;
    #pragma unroll
    for (int q = 0; q < 2; ++q) {
      const int kk = q * 512 + tid;
      const int hs = kk >> 9, dim = kk & 511;
      const float* hp = &p.hfin[((size_t)hs * NB + b) * NH + dim];
      const float hv = __hip_atomic_load(hp, __ATOMIC_RELAXED, __HIP_MEMORY_SCOPE_AGENT);
      a0 += hv * p.Wd[kk * 3 + 0];
      a1 += hv * p.Wd[kk * 3 + 1];
      a2 += hv * p.Wd[kk * 3 + 2];
    }
    #pragma unroll
    for (int s = 32; s > 0; s >>= 1) {
      a0 += __shfl_down(a0, s, 64);
      a1 += __shfl_down(a1, s, 64);
      a2 += __shfl_down(a2, s, 64);
    }
    if (ln == 0) { redL[wv][0] = a0; redL[wv][1] = a1; redL[wv][2] = a2; }
    __syncthreads();
    if (tid == 0) {
      float o0 = p.bd[0], o1 = p.bd[1], o2 = p.bd[2];
      #pragma unroll
      for (int w = 0; w < 8; ++w) { o0 += redL[w][0]; o1 += redL[w][1]; o2 += redL[w][2]; }
      p.out[b * 3 + 0] = o0;
      p.out[b * 3 + 1] = o1;
      p.out[b * 3 + 2] = o2;
    }
  }
}

extern "C" void kernel_launch(void* const* d_in, const int* in_sizes, int n_in,
                              void* d_out, int out_size, void* d_ws, size_t ws_size,
                              hipStream_t stream) {
  (void)in_sizes; (void)n_in; (void)out_size; (void)ws_size;
  char* ws = (char*)d_ws;
  Params p;
  p.tids = (const int*)d_in[0];
  p.tlen = (const int*)d_in[1];
  p.lids = (const int*)d_in[2];
  p.llen = (const int*)d_in[3];
  p.rids = (const int*)d_in[4];
  p.rlen = (const int*)d_in[5];
  p.emb  = (const float*)d_in[6];
  p.Wl   = (const float*)d_in[7];
  p.bl   = (const float*)d_in[8];
  p.Wr   = (const float*)d_in[9];
  p.br   = (const float*)d_in[10];
  p.Wd   = (const float*)d_in[11];
  p.bd   = (const float*)d_in[12];
  p.out  = (float*)d_out;
  p.bar  = (int*)ws;                                   // 16 x 4KB = 65,536 B
  p.hbuf = (unsigned short*)(ws + 65536);              // 2*2*128*512*2 = 524,288 B
  p.hfin = (float*)(ws + 65536 + 524288);              // 2*128*512*4   = 524,288 B
  // zero flags AND hbuf (stale tags must mismatch across runs/replays)
  hipMemsetAsync(ws, 0, 65536 + 524288, stream);
  lstm_all<<<dim3(256), dim3(512), 0, stream>>>(p);
}

// Round 15
// 421.798 us; speedup vs baseline: 1.0981x; 1.0981x over previous
//
#include <hip/hip_runtime.h>

#define NB 128   // batch
#define NS 128   // context seq len
#define NT 12    // target seq len
#define NE 300   // embed dim
#define NH 512   // hidden
#define NCOL 2048  // 4*NH
#define WGSC __HIP_MEMORY_SCOPE_WORKGROUP

typedef _Float16 h8v __attribute__((ext_vector_type(8)));
typedef __attribute__((ext_vector_type(4))) float f4v;
typedef __attribute__((ext_vector_type(4))) int   i4v;

__device__ __forceinline__ unsigned short f2h(float f) {
  union { _Float16 h; unsigned short u; } c; c.h = (_Float16)f; return c.u;
}
__device__ __forceinline__ float sigm(float x) { return 1.f / (1.f + __expf(-x)); }
__device__ __forceinline__ float tanh_(float x) { const float e = __expf(2.f * x); return 1.f - 2.f / (e + 1.f); }

// pack two f16 h-values into a dword, stealing each mantissa LSB for a 2-bit step tag
__device__ __forceinline__ unsigned packh(float a, float b, int tag) {
  unsigned lo = f2h(a), hi = f2h(b);
  lo = (lo & ~1u) | (unsigned)(tag & 1);
  hi = (hi & ~1u) | (unsigned)((tag >> 1) & 1);
  return lo | (hi << 16);
}

// ---- device-scope UNCACHED (sc1, coherence at IF/L3) primitives ----
__device__ __forceinline__ void st32f_uc(float* p, float v) {
  asm volatile("global_store_dword %0, %1, off sc1" :: "v"(p), "v"(v) : "memory");
}
__device__ __forceinline__ void st32i_uc(int* p, int v) {
  asm volatile("global_store_dword %0, %1, off sc1" :: "v"(p), "v"(v) : "memory");
}
__device__ __forceinline__ void st32u_uc(unsigned* p, unsigned v) {
  asm volatile("global_store_dword %0, %1, off sc1" :: "v"(p), "v"(v) : "memory");
}
__device__ __forceinline__ int ldflag(const int* p) {
  int v;
  asm volatile("global_load_dword %0, %1, off sc1\n\ts_waitcnt vmcnt(0)" : "=v"(v) : "v"(p) : "memory");
  return v;
}
// 4 x 16B sc1 loads of one contiguous 64B chunk, one vmcnt
__device__ __forceinline__ void ld64_uc(const char* a, i4v* r) {
  asm volatile(
    "global_load_dwordx4 %0, %4, off sc1\n\t"
    "global_load_dwordx4 %1, %4, off offset:16 sc1\n\t"
    "global_load_dwordx4 %2, %4, off offset:32 sc1\n\t"
    "global_load_dwordx4 %3, %4, off offset:48 sc1\n\t"
    "s_waitcnt vmcnt(0)"
    : "=&v"(r[0]), "=&v"(r[1]), "=&v"(r[2]), "=&v"(r[3])
    : "v"(a) : "memory");
}

struct Params {
  const int *tids, *tlen, *lids, *llen, *rids, *rlen;
  const float *emb, *Wl, *bl, *Wr, *br, *Wd, *bd;
  float* out;
  unsigned short* hbuf;  // [2(pp)][2(side)][NB][NH] f16 tagged (sc1; zeroed each launch)
  float* hfin;           // [2(side)][NB][NH] fp32 (sc1)
  int* bar;              // flags: [16 groups] x 4KB page (epilogue only)
};

__device__ __forceinline__ void lspin(int* c, int tgt) {
  while (__hip_atomic_load(c, __ATOMIC_RELAXED, WGSC) < tgt) {}
  __builtin_amdgcn_fence(__ATOMIC_ACQUIRE, "workgroup");
}
// sleepy variant for x-role waits (frees SIMD issue slots for co-resident h-wave)
__device__ __forceinline__ void lspin_s(int* c, int tgt) {
  while (__hip_atomic_load(c, __ATOMIC_RELAXED, WGSC) < tgt)
    __builtin_amdgcn_s_sleep(1);
  __builtin_amdgcn_fence(__ATOMIC_ACQUIRE, "workgroup");
}
__device__ __forceinline__ void larrive(int* c) {
  __hip_atomic_fetch_add(c, 1, __ATOMIC_ACQ_REL, WGSC);
}

// LDS layout (main loop):
//   HS   @ 0     : 16 rows x 1024B f16, XOR-swizzled (h staging)   16384
//   XS   @ 16384 : 16 rows x 640B f16, XOR-swizzled (x staging)    10240
//   ZX   @ 26624 : 3-slot ring, [16][128] f32 (8KB/slot)           24576
//   ZS   @ 51200 : [16][128] f32 gate exchange                      8192
// prologue aliases (dead before first conflicting use):
//   meanF16 [16][640B swizzled] @ OFF_HS (dead before t=1 h staging)
//   WTH @ 51200 (ZS) ; WTX @ 34816 (ZX slot1)
#define OFF_HS   0
#define OFF_XS   16384
#define OFF_ZX   26624
#define OFF_ZS   51200
#define OFF_WTH  51200
#define OFF_WTX  34816
#define LDS_SZ   59392

__global__ __launch_bounds__(512, 1) void lstm_all(Params p) {
  __shared__ __align__(16) char lds[LDS_SZ];
  __shared__ int lenL[16];
  __shared__ float redL[8][4];
  __shared__ int cnt[8];   // 0:stage 1:xbar 2:prod 3:cons 4:zsbar 5:epi 7:hpbar

  const int tid = threadIdx.x;
  const int wid = blockIdx.x;
  if (tid < 8) cnt[tid] = 0;

  // group g = wid&15 (side=g&1, bt=g>>1: 16 batch rows), dim-block ht = wid>>4 (32 dims)
  const int g = wid & 15, ht = wid >> 4;
  const int side = g & 1, bt = g >> 1;
  const int b0 = bt * 16, d0c = ht * 32;
  const int* lenp = side ? p.rlen : p.llen;
  const int* gids = side ? p.rids : p.lids;
  const float* W = side ? p.Wr : p.Wl;
  const float* bias = side ? p.br : p.bl;
  int* fl = p.bar + g * 1024;

  const bool isH = tid < 256;          // waves 0-3: h recurrence; 4-7: x pipeline
  const int wv = tid >> 6;
  const int ln = tid & 63;
  const int lwv = isH ? wv : (wv - 4); // role-local wave = GATE index (0..3)
  const int kgrp = ln >> 4;
  const int stid = tid & 255;

  float* zS = (float*)(lds + OFF_ZS);

  // ---------------- phase 1: mean_t -> f16 row-major swizzled @ OFF_HS ----------------
  {
    const int r = tid >> 5, l32 = tid & 31;
    const int b = b0 + r;
    const int Lt = p.tlen[b];
    const float inv = 1.f / (float)Lt;
    int toks[NT];
    #pragma unroll
    for (int t = 0; t < NT; ++t) toks[t] = p.tids[b * NT + t];
    char* mrow = lds + OFF_HS + r * 640;
    for (int k = l32; k < 320; k += 32) {
      unsigned short hv = 0;
      if (k < 300) {
        float s = 0.f;
        #pragma unroll
        for (int t = 0; t < NT; ++t)
          if (t < Lt) s += p.emb[(size_t)toks[t] * NE + k];
        hv = f2h(s * inv);
      }
      const int c16 = k >> 3;
      *(unsigned short*)(mrow + ((c16 * 16) ^ ((r & 7) << 4)) + (k & 7) * 2) = hv;
    }
    if (tid < 16) lenL[tid] = lenp[b0 + tid];
  }
  __syncthreads();   // the ONLY block-wide barrier before the dense head

  if (isH) {
    // ================= h role (waves 0-3; wave w owns gate w) =================
    const int row_c = stid >> 4;       // cell row 0..15
    const int m = stid & 15;           // cell dim pair (2m, 2m+1)
    const int a_r = ln & 15;           // A-frag row

    int he = 0;
    auto hpbar = [&]() {
      ++he;
      if (ln == 0) larrive(&cnt[7]);
      while (__hip_atomic_load(&cnt[7], __ATOMIC_RELAXED, WGSC) < 4 * he) {}
      __builtin_amdgcn_fence(__ATOMIC_ACQUIRE, "workgroup");
    };

    // -------- phase 3m: Wm (W rows 300..619) -> transient frags, zb via MFMA --------
    // mean f16 pad (k 300..319) is ZERO, so W rows 600..619 contribute exactly 0.
    float zb1[4], zb2[4];
    {
      h8v mfr0[10], mfr1[10];
      unsigned short* wT = (unsigned short*)(lds + OFF_WTH);   // [128 cols][32 k]
      const int r3 = stid >> 3;
      const int part = stid & 7;
      const int gate_p = part >> 1, half_p = part & 1;
      for (int i = 0; i < 10; ++i) {
        const int k = 300 + i * 32 + r3;    // <= 619, valid memory
        const float* wr = W + (size_t)k * NCOL + gate_p * NH + d0c + half_p * 16;
        const f4v a0 = *(const f4v*)wr;
        const f4v a1 = *(const f4v*)(wr + 4);
        const f4v a2 = *(const f4v*)(wr + 8);
        const f4v a3 = *(const f4v*)(wr + 12);
        #pragma unroll
        for (int j = 0; j < 4; ++j) {
          wT[(part * 16 + j) * 32 + r3]      = f2h(a0[j]);
          wT[(part * 16 + 4 + j) * 32 + r3]  = f2h(a1[j]);
          wT[(part * 16 + 8 + j) * 32 + r3]  = f2h(a2[j]);
          wT[(part * 16 + 12 + j) * 32 + r3] = f2h(a3[j]);
        }
        hpbar();
        const int c0 = lwv * 32 + (ln & 15);
        mfr0[i] = *(const h8v*)((char*)wT + c0 * 64 + kgrp * 16);
        mfr1[i] = *(const h8v*)((char*)wT + (c0 + 16) * 64 + kgrp * 16);
        hpbar();
      }
      // zb = mean @ W[300:600] via 20 MFMAs (A from meanF16 @ OFF_HS)
      f4v acc0 = {0.f, 0.f, 0.f, 0.f}, acc1 = {0.f, 0.f, 0.f, 0.f};
      #pragma unroll
      for (int kt = 0; kt < 10; ++kt) {
        h8v a = *(const h8v*)(lds + OFF_HS + a_r * 640
                              + (((kt * 4 + kgrp) * 16) ^ ((a_r & 7) << 4)));
        acc0 = __builtin_amdgcn_mfma_f32_16x16x32_f16(a, mfr0[kt], acc0, 0, 0, 0);
        acc1 = __builtin_amdgcn_mfma_f32_16x16x32_f16(a, mfr1[kt], acc1, 0, 0, 0);
      }
      // redistribute through zS (WTH dead after last hpbar)
      #pragma unroll
      for (int rg = 0; rg < 4; ++rg) {
        const int rr = kgrp * 4 + rg;
        zS[rr * 128 + lwv * 32 + (ln & 15)]      = acc0[rg];
        zS[rr * 128 + lwv * 32 + 16 + (ln & 15)] = acc1[rg];
      }
      hpbar();
      #pragma unroll
      for (int gq = 0; gq < 4; ++gq) {
        zb1[gq] = zS[row_c * 128 + gq * 32 + 2 * m]     + bias[gq * NH + d0c + 2 * m];
        zb2[gq] = zS[row_c * 128 + gq * 32 + 2 * m + 1] + bias[gq * NH + d0c + 2 * m + 1];
      }
      hpbar();   // zb reads retired before phase 3h reuses WTH (= zS region)
    }

    // -------- phase 3h: Wh -> register B-fragments (16 K-tiles x 2 N-tiles) --------
    h8v hfr0[16], hfr1[16];
    {
      unsigned short* wT = (unsigned short*)(lds + OFF_WTH);   // [128 cols][32 k]
      const int r3 = stid >> 3;
      const int part = stid & 7;
      const int gate_p = part >> 1, half_p = part & 1;
      for (int i = 0; i < 16; ++i) {
        const int k = 600 + i * 32 + r3;
        const float* wr = W + (size_t)k * NCOL + gate_p * NH + d0c + half_p * 16;
        const f4v a0 = *(const f4v*)wr;
        const f4v a1 = *(const f4v*)(wr + 4);
        const f4v a2 = *(const f4v*)(wr + 8);
        const f4v a3 = *(const f4v*)(wr + 12);
        #pragma unroll
        for (int j = 0; j < 4; ++j) {
          wT[(part * 16 + j) * 32 + r3]      = f2h(a0[j]);
          wT[(part * 16 + 4 + j) * 32 + r3]  = f2h(a1[j]);
          wT[(part * 16 + 8 + j) * 32 + r3]  = f2h(a2[j]);
          wT[(part * 16 + 12 + j) * 32 + r3] = f2h(a3[j]);
        }
        hpbar();
        const int c0 = lwv * 32 + (ln & 15);
        hfr0[i] = *(const h8v*)((char*)wT + c0 * 64 + kgrp * 16);
        hfr1[i] = *(const h8v*)((char*)wT + (c0 + 16) * 64 + kgrp * 16);
        hpbar();
      }
    }

    // -------- main recurrence --------
    float cR1 = 0.f, cR2 = 0.f, hR1 = 0.f, hR2 = 0.f;
    const int srow = stid >> 4;                      // staging row (== row_c)
    const int schk = stid & 15;                      // staging 64B chunk
    for (int t = 0; t < NS; ++t) {
      // 1. zx(t) from ring
      lspin(&cnt[2], 4 * (t + 1));
      const float* zx = (const float*)(lds + OFF_ZX + (t % 3) * 8192);
      f4v acc0, acc1;
      #pragma unroll
      for (int rg = 0; rg < 4; ++rg) {
        const int rr = kgrp * 4 + rg;
        acc0[rg] = zx[rr * 128 + lwv * 32 + (ln & 15)];
        acc1[rg] = zx[rr * 128 + lwv * 32 + 16 + (ln & 15)];
      }
      if (ln == 0) larrive(&cnt[3]);

      // 2. poll-validate h_t (tag = t&3 embedded in data), stage -> HS, barrier, MFMA
      if (t) {
        const char* src = (const char*)(p.hbuf
            + (size_t)(((t & 1) * 2 + side) * NB + b0 + srow) * NH + schk * 32);
        const unsigned exp32 = ((unsigned)(t & 1)) | (((unsigned)((t >> 1) & 1)) << 16);
        i4v v[4];
        for (;;) {
          ld64_uc(src, v);
          unsigned bad = 0;
          #pragma unroll
          for (int q = 0; q < 4; ++q)
            #pragma unroll
            for (int j = 0; j < 4; ++j)
              bad |= (((unsigned)v[q][j]) ^ exp32) & 0x00010001u;
          if (!bad) break;
        }
        #pragma unroll
        for (int q = 0; q < 4; ++q) {
          const int c16 = schk * 4 + q;
          *(i4v*)(lds + OFF_HS + srow * 1024 + ((c16 * 16) ^ ((srow & 7) << 4))) = v[q];
        }
        if (ln == 0) larrive(&cnt[0]);
        while (__hip_atomic_load(&cnt[0], __ATOMIC_RELAXED, WGSC) < 4 * t) {}
        __builtin_amdgcn_fence(__ATOMIC_ACQUIRE, "workgroup");
        #pragma unroll
        for (int kt = 0; kt < 16; ++kt) {
          h8v a = *(const h8v*)(lds + OFF_HS + a_r * 1024
                                + (((kt * 4 + kgrp) * 16) ^ ((a_r & 7) << 4)));
          acc0 = __builtin_amdgcn_mfma_f32_16x16x32_f16(a, hfr0[kt], acc0, 0, 0, 0);
          acc1 = __builtin_amdgcn_mfma_f32_16x16x32_f16(a, hfr1[kt], acc1, 0, 0, 0);
        }
      }

      // 3. gate exchange (wave w -> zS cols of gate w)
      #pragma unroll
      for (int rg = 0; rg < 4; ++rg) {
        const int rr = kgrp * 4 + rg;
        zS[rr * 128 + lwv * 32 + (ln & 15)]      = acc0[rg];
        zS[rr * 128 + lwv * 32 + 16 + (ln & 15)] = acc1[rg];
      }
      if (ln == 0) larrive(&cnt[4]);
      while (__hip_atomic_load(&cnt[4], __ATOMIC_RELAXED, WGSC) < 4 * (t + 1)) {}
      __builtin_amdgcn_fence(__ATOMIC_ACQUIRE, "workgroup");

      // 4. cell update (row_c, dims 2m/2m+1); tagged coalesced dword store, NO drain/flag
      {
        const float* zr = zS + row_c * 128;
        float zi = zr[0 * 32 + 2 * m] + zb1[0], zj = zr[1 * 32 + 2 * m] + zb1[1];
        float zf = zr[2 * 32 + 2 * m] + zb1[2], zo = zr[3 * 32 + 2 * m] + zb1[3];
        float ig = sigm(zi), jg = tanh_(zj), fg = sigm(zf + 1.f), og = sigm(zo);
        float cn = fg * cR1 + ig * jg;
        float hn = og * tanh_(cn);
        if (t < lenL[row_c]) { cR1 = cn; hR1 = hn; }
        zi = zr[0 * 32 + 2 * m + 1] + zb2[0]; zj = zr[1 * 32 + 2 * m + 1] + zb2[1];
        zf = zr[2 * 32 + 2 * m + 1] + zb2[2]; zo = zr[3 * 32 + 2 * m + 1] + zb2[3];
        ig = sigm(zi); jg = tanh_(zj); fg = sigm(zf + 1.f); og = sigm(zo);
        cn = fg * cR2 + ig * jg; hn = og * tanh_(cn);
        if (t < lenL[row_c]) { cR2 = cn; hR2 = hn; }
        unsigned pk = packh(hR1, hR2, (t + 1) & 3);
        unsigned* dst = (unsigned*)p.hbuf
            + ((size_t)((((t + 1) & 1) * 2 + side) * NB + b0 + row_c) * (NH / 2)) + d0c / 2 + m;
        st32u_uc(dst, pk);
      }
    }

    // -------- epilogue: final h -> hfin (sc1, clean fp32), then flag NS+1 --------
    st32f_uc(&p.hfin[((size_t)side * NB + b0 + row_c) * NH + d0c + 2 * m], hR1);
    st32f_uc(&p.hfin[((size_t)side * NB + b0 + row_c) * NH + d0c + 2 * m + 1], hR2);
    asm volatile("s_waitcnt vmcnt(0)" ::: "memory");
    if (ln == 0) larrive(&cnt[5]);
    if (lwv == 0) {
      while (__hip_atomic_load(&cnt[5], __ATOMIC_RELAXED, WGSC) < 4) {}
      if (ln == 0) st32i_uc(fl + ht, NS + 1);
    }
  } else {
    // ================= x role (waves 4-7; wave owns gate lwv) =================
    int xe = 0;
    auto xbar = [&]() {
      ++xe;
      if (ln == 0) larrive(&cnt[1]);
      while (__hip_atomic_load(&cnt[1], __ATOMIC_RELAXED, WGSC) < 4 * xe)
        __builtin_amdgcn_s_sleep(1);
      __builtin_amdgcn_fence(__ATOMIC_ACQUIRE, "workgroup");
    };

    // -------- phase 3x: Wx -> register B-fragments (10 K-tiles x 2 N-tiles) --------
    h8v xfr0[10], xfr1[10];
    {
      unsigned short* wT = (unsigned short*)(lds + OFF_WTX);   // [128 cols][32 k]
      const int r3 = stid >> 3, part = stid & 7;
      const int gate_p = part >> 1, half_p = part & 1;
      for (int i = 0; i < 10; ++i) {
        const int k = i * 32 + r3;
        float v[16];
        if (k < NE) {
          const float* wr = W + (size_t)k * NCOL + gate_p * NH + d0c + half_p * 16;
          const f4v a0 = *(const f4v*)wr;
          const f4v a1 = *(const f4v*)(wr + 4);
          const f4v a2 = *(const f4v*)(wr + 8);
          const f4v a3 = *(const f4v*)(wr + 12);
          #pragma unroll
          for (int j = 0; j < 4; ++j) {
            v[j] = a0[j]; v[4 + j] = a1[j]; v[8 + j] = a2[j]; v[12 + j] = a3[j];
          }
        } else {
          #pragma unroll
          for (int j = 0; j < 16; ++j) v[j] = 0.f;
        }
        #pragma unroll
        for (int j = 0; j < 16; ++j)
          wT[(part * 16 + j) * 32 + r3] = f2h(v[j]);
        xbar();
        const int c0 = lwv * 32 + (ln & 15);
        xfr0[i] = *(const h8v*)((char*)wT + c0 * 64 + kgrp * 16);
        xfr1[i] = *(const h8v*)((char*)wT + (c0 + 16) * 64 + kgrp * 16);
        xbar();
      }
    }

    // -------- x pipeline: produce zx(n) = x_n @ Wx, up to 3 ahead --------
    // (XS is free from the start: meanF16 lives in the HS region)
    for (int n = 0; n < NS; ++n) {
      if (n >= 3) lspin_s(&cnt[3], 4 * (n - 2));   // ring slot n%3 free (sleepy)
      {
        const int xrow = stid >> 4;              // 16 rows, 16 lanes each
        const int tok = gids[(size_t)(b0 + xrow) * NS + n];
        const float* ep_ = p.emb + (size_t)tok * NE;
        #pragma unroll
        for (int j = 0; j < 3; ++j) {
          const int c16 = (stid & 15) + j * 16;
          if (c16 < 40) {
            unsigned short tmp[8];
            if (c16 < 37) {
              const f4v v0 = *(const f4v*)(ep_ + c16 * 8);
              const f4v v1 = *(const f4v*)(ep_ + c16 * 8 + 4);
              tmp[0] = f2h(v0[0]); tmp[1] = f2h(v0[1]); tmp[2] = f2h(v0[2]); tmp[3] = f2h(v0[3]);
              tmp[4] = f2h(v1[0]); tmp[5] = f2h(v1[1]); tmp[6] = f2h(v1[2]); tmp[7] = f2h(v1[3]);
            } else if (c16 == 37) {
              const f4v v0 = *(const f4v*)(ep_ + 296);
              tmp[0] = f2h(v0[0]); tmp[1] = f2h(v0[1]); tmp[2] = f2h(v0[2]); tmp[3] = f2h(v0[3]);
              tmp[4] = 0; tmp[5] = 0; tmp[6] = 0; tmp[7] = 0;
            } else {
              #pragma unroll
              for (int q = 0; q < 8; ++q) tmp[q] = 0;
            }
            *(i4v*)(lds + OFF_XS + xrow * 640 + ((c16 * 16) ^ ((xrow & 7) << 4))) = *(const i4v*)tmp;
          }
        }
      }
      xbar();
      f4v a0 = {0.f, 0.f, 0.f, 0.f}, a1 = {0.f, 0.f, 0.f, 0.f};
      const int a_r = ln & 15;
      #pragma unroll
      for (int kt = 0; kt < 10; ++kt) {
        h8v a = *(const h8v*)(lds + OFF_XS + a_r * 640
                              + (((kt * 4 + kgrp) * 16) ^ ((a_r & 7) << 4)));
        a0 = __builtin_amdgcn_mfma_f32_16x16x32_f16(a, xfr0[kt], a0, 0, 0, 0);
        a1 = __builtin_amdgcn_mfma_f32_16x16x32_f16(a, xfr1[kt], a1, 0, 0, 0);
      }
      float* zx = (float*)(lds + OFF_ZX + (n % 3) * 8192);
      #pragma unroll
      for (int rg = 0; rg < 4; ++rg) {
        const int rr = kgrp * 4 + rg;
        zx[rr * 128 + lwv * 32 + (ln & 15)]      = a0[rg];
        zx[rr * 128 + lwv * 32 + 16 + (ln & 15)] = a1[rg];
      }
      if (ln == 0) larrive(&cnt[2]);
      xbar();   // xS reads retired before next gather
    }
  }

  // ---------------- dense head (blocks 0..127, all 512 threads) ----------------
  if (wid < NB) {
    const int b = wid, bth = b >> 4;
    if (tid < 32) {
      const int gh = (bth << 1) + (tid >> 4);    // side = tid>>4
      const int* f = p.bar + gh * 1024 + (tid & 15);
      int v = ldflag(f);
      while (__ballot(v < NS + 1) != 0ull) { __builtin_amdgcn_s_sleep(2); v = ldflag(f); }
    }
    __syncthreads();

    float a0 = 0.f, a1 = 0.f, a2 = 0.f;
    #pragma unroll
    for (int q = 0; q < 2; ++q) {
      const int kk = q * 512 + tid;
      const int hs = kk >> 9, dim = kk & 511;
      const float* hp = &p.hfin[((size_t)hs * NB + b) * NH + dim];
      const float hv = __hip_atomic_load(hp, __ATOMIC_RELAXED, __HIP_MEMORY_SCOPE_AGENT);
      a0 += hv * p.Wd[kk * 3 + 0];
      a1 += hv * p.Wd[kk * 3 + 1];
      a2 += hv * p.Wd[kk * 3 + 2];
    }
    #pragma unroll
    for (int s = 32; s > 0; s >>= 1) {
      a0 += __shfl_down(a0, s, 64);
      a1 += __shfl_down(a1, s, 64);
      a2 += __shfl_down(a2, s, 64);
    }
    if (ln == 0) { redL[wv][0] = a0; redL[wv][1] = a1; redL[wv][2] = a2; }
    __syncthreads();
    if (tid == 0) {
      float o0 = p.bd[0], o1 = p.bd[1], o2 = p.bd[2];
      #pragma unroll
      for (int w = 0; w < 8; ++w) { o0 += redL[w][0]; o1 += redL[w][1]; o2 += redL[w][2]; }
      p.out[b * 3 + 0] = o0;
      p.out[b * 3 + 1] = o1;
      p.out[b * 3 + 2] = o2;
    }
  }
}

extern "C" void kernel_launch(void* const* d_in, const int* in_sizes, int n_in,
                              void* d_out, int out_size, void* d_ws, size_t ws_size,
                              hipStream_t stream) {
  (void)in_sizes; (void)n_in; (void)out_size; (void)ws_size;
  char* ws = (char*)d_ws;
  Params p;
  p.tids = (const int*)d_in[0];
  p.tlen = (const int*)d_in[1];
  p.lids = (const int*)d_in[2];
  p.llen = (const int*)d_in[3];
  p.rids = (const int*)d_in[4];
  p.rlen = (const int*)d_in[5];
  p.emb  = (const float*)d_in[6];
  p.Wl   = (const float*)d_in[7];
  p.bl   = (const float*)d_in[8];
  p.Wr   = (const float*)d_in[9];
  p.br   = (const float*)d_in[10];
  p.Wd   = (const float*)d_in[11];
  p.bd   = (const float*)d_in[12];
  p.out  = (float*)d_out;
  p.bar  = (int*)ws;                                   // 16 x 4KB = 65,536 B
  p.hbuf = (unsigned short*)(ws + 65536);              // 2*2*128*512*2 = 524,288 B
  p.hfin = (float*)(ws + 65536 + 524288);              // 2*128*512*4   = 524,288 B
  // zero flags AND hbuf (stale tags must mismatch across runs/replays)
  hipMemsetAsync(ws, 0, 65536 + 524288, stream);
  lstm_all<<<dim3(256), dim3(512), 0, stream>>>(p);
}